// Round 1
// baseline (1723.587 us; speedup 1.0000x reference)
//
#include <hip/hip_runtime.h>

// ws layout (floats): [0..63] future_load | [64..127] P sums | [128..191] top-k counts | [192] comp sum

__device__ __forceinline__ float rlf(float v, int l) {
  return __int_as_float(__builtin_amdgcn_readlane(__float_as_int(v), l));
}
__device__ __forceinline__ float wsum(float v) {
#pragma unroll
  for (int o = 32; o; o >>= 1) v += __shfl_xor(v, o, 64);
  return v;
}
__device__ __forceinline__ float wmax(float v) {
#pragma unroll
  for (int o = 32; o; o >>= 1) v = fmaxf(v, __shfl_xor(v, o, 64));
  return v;
}

// ---------------- Kernel 1: LSTM load predictor + future_load softmax ----------------
// One block, 256 threads. thread g owns gate g (rows of w_ih/w_hh in VGPRs).
// Recurrent/input vectors broadcast via v_readlane (no LDS throughput cost).
__global__ __launch_bounds__(256) void lstm_kernel(
    const float* __restrict__ lb,
    const float* __restrict__ wih0, const float* __restrict__ whh0,
    const float* __restrict__ bih0, const float* __restrict__ bhh0,
    const float* __restrict__ wih1, const float* __restrict__ whh1,
    const float* __restrict__ bih1, const float* __restrict__ bhh1,
    const float* __restrict__ head_w, const float* __restrict__ head_b,
    float* __restrict__ ws, float* __restrict__ out, int N)
{
  const int tid = threadIdx.x;
  const int lane = tid & 63;
  __shared__ float seqh[50 * 64];
  __shared__ float h1s[50 * 64];
  __shared__ float zbuf[256];
  __shared__ float hbuf[64];
  __shared__ float preds[640];

  // zero ws accumulators (K2 atomically adds into these)
  if (tid < 129) ws[64 + tid] = 0.f;
  for (int i = tid; i < 3200; i += 256) seqh[i] = lb[i];

  float hv = 0.f;
#pragma unroll 1
  for (int L = 0; L < 2; ++L) {
    const float* wip  = L ? wih1 : wih0;
    const float* whp  = L ? whh1 : whh0;
    const float* bip  = L ? bih1 : bih0;
    const float* bhp  = L ? bhh1 : bhh0;
    const float* seqp = L ? h1s  : seqh;
    float wiR[64], whR[64];
#pragma unroll
    for (int j = 0; j < 64; j += 4) {
      *(float4*)&wiR[j] = *(const float4*)(wip + tid * 64 + j);
      *(float4*)&whR[j] = *(const float4*)(whp + tid * 64 + j);
    }
    const float bsum = bip[tid] + bhp[tid];
    float c_reg = 0.f;
    hv = 0.f;
    if (tid < 64) hbuf[tid] = 0.f;
    __syncthreads();
#pragma unroll 1
    for (int t = 0; t < 50; ++t) {
      const float xv = seqp[t * 64 + lane];
      float a0 = bsum, a1 = 0.f, a2 = 0.f, a3 = 0.f;
#pragma unroll
      for (int j = 0; j < 64; j += 4) {
        a0 = fmaf(rlf(xv, j + 0), wiR[j + 0], a0);
        a1 = fmaf(rlf(xv, j + 1), wiR[j + 1], a1);
        a2 = fmaf(rlf(xv, j + 2), wiR[j + 2], a2);
        a3 = fmaf(rlf(xv, j + 3), wiR[j + 3], a3);
      }
#pragma unroll
      for (int j = 0; j < 64; j += 4) {
        a0 = fmaf(rlf(hv, j + 0), whR[j + 0], a0);
        a1 = fmaf(rlf(hv, j + 1), whR[j + 1], a1);
        a2 = fmaf(rlf(hv, j + 2), whR[j + 2], a2);
        a3 = fmaf(rlf(hv, j + 3), whR[j + 3], a3);
      }
      zbuf[tid] = (a0 + a1) + (a2 + a3);
      __syncthreads();
      if (tid < 64) {
        const float zi = zbuf[tid], zf = zbuf[64 + tid];
        const float zg = zbuf[128 + tid], zo = zbuf[192 + tid];
        const float si = 1.f / (1.f + expf(-zi));
        const float sf = 1.f / (1.f + expf(-zf));
        const float so = 1.f / (1.f + expf(-zo));
        c_reg = sf * c_reg + si * tanhf(zg);
        const float h = so * tanhf(c_reg);
        hbuf[tid] = h;
        if (L == 0) h1s[t * 64 + tid] = h;
      }
      __syncthreads();
      hv = hbuf[lane];
    }
    __syncthreads();  // protect hbuf re-init next layer
  }
  // head: pred[o] = h2 . head_w[o] + head_b[o]
  for (int o = tid; o < 640; o += 256) {
    const float* hw = head_w + o * 64;
    float a0 = 0.f, a1 = 0.f, a2 = 0.f, a3 = 0.f;
#pragma unroll
    for (int j = 0; j < 64; j += 4) {
      a0 = fmaf(rlf(hv, j + 0), hw[j + 0], a0);
      a1 = fmaf(rlf(hv, j + 1), hw[j + 1], a1);
      a2 = fmaf(rlf(hv, j + 2), hw[j + 2], a2);
      a3 = fmaf(rlf(hv, j + 3), hw[j + 3], a3);
    }
    preds[o] = (a0 + a1) + (a2 + a3) + head_b[o];
  }
  __syncthreads();
  if (tid < 64) {
    float m = 0.f;
#pragma unroll
    for (int h = 0; h < 10; ++h) m += preds[tid * 10 + h];
    m = m / 10.f;
    const float mx = wmax(m);
    const float p = expf(m - mx);
    const float s = wsum(p);
    const float flv = p / s;
    ws[tid] = flv;
    out[4 * N + 2 + tid] = flv;
  }
}

// ---------------- Kernel 2: fused gate+cp GEMM, softmax, top-2, partial sums ----------
// 512 thr = 8 waves = 2 output-halves x 4 K-quarters over a 64-token tile. lane = token.
// W operand via wave-uniform scalar loads (SGPR broadcast); LDS only stages x (pad-68 rows).
__global__ __launch_bounds__(512) void moe_kernel(
    const float* __restrict__ x, const float* __restrict__ gate_w,
    const float* __restrict__ eb_p, const float* __restrict__ cp_w1,
    const float* __restrict__ cp_b1, const float* __restrict__ cp_w2,
    const float* __restrict__ cp_b2, float* __restrict__ ws,
    float* __restrict__ out, int N)
{
  const int tid = threadIdx.x;
  const int lane = tid & 63;
  const int w = __builtin_amdgcn_readfirstlane(tid >> 6);
  const int oh = w & 1, kq = w >> 1;
  const int tb = blockIdx.x * 64;

  __shared__ __align__(16) float sbuf[2][64][68];
  __shared__ __align__(16) float souts[64][132];
  __shared__ float sP[64];
  __shared__ unsigned scnt[64];
  __shared__ float scomp;

  // staging role: 8 threads per token row; 4 quarters x 2 halves of 16 floats
  const int row = tid >> 3;
  const int s8 = tid & 7;
  const int q = s8 >> 1, hf = s8 & 1;
  const float* gbase = x + (size_t)(tb + row) * 4096 + q * 1024 + hf * 8;

  float acc[64];
#pragma unroll
  for (int m = 0; m < 64; ++m) acc[m] = 0.f;

  const float* wsel = oh ? cp_w1 : gate_w;
  const float* wq = wsel + kq * 1024;

  {  // prologue: stage chunk 0
    const float4* gp = reinterpret_cast<const float4*>(gbase);
    float4 v0 = gp[0], v1 = gp[1];
    float4* sp = reinterpret_cast<float4*>(&sbuf[0][row][q * 16 + hf * 8]);
    sp[0] = v0; sp[1] = v1;
  }
  __syncthreads();

  int buf = 0;
#pragma unroll 1
  for (int c = 0; c < 64; ++c) {
    float4 v0, v1;
    if (c < 63) {  // issue next-chunk loads early; HBM latency hides under FMA block
      const float4* gp = reinterpret_cast<const float4*>(gbase + (c + 1) * 16);
      v0 = gp[0]; v1 = gp[1];
    }
    float xr[16];
    {
      const float4* xs = reinterpret_cast<const float4*>(&sbuf[buf][lane][kq * 16]);
      *(float4*)&xr[0] = xs[0]; *(float4*)&xr[4] = xs[1];
      *(float4*)&xr[8] = xs[2]; *(float4*)&xr[12] = xs[3];
    }
    const float* wb = wq + c * 16;
#pragma unroll
    for (int m = 0; m < 64; ++m) {
      const float* wr = wb + (size_t)m * 4096;  // wave-uniform -> s_load
      float s0 = acc[m];
#pragma unroll
      for (int kk = 0; kk < 16; ++kk) s0 = fmaf(xr[kk], wr[kk], s0);
      acc[m] = s0;
    }
    if (c < 63) {
      float4* sp = reinterpret_cast<float4*>(&sbuf[buf ^ 1][row][q * 16 + hf * 8]);
      sp[0] = v0; sp[1] = v1;
    }
    __syncthreads();
    buf ^= 1;
  }

  // zero souts + init block reducers
  for (int i = tid; i < 64 * 132; i += 512) (&souts[0][0])[i] = 0.f;
  if (tid < 64) { sP[tid] = 0.f; scnt[tid] = 0u; }
  if (tid == 0) scomp = 0.f;
  __syncthreads();

  // K-quarter reduction into souts[token][128]
#pragma unroll 1
  for (int r = 0; r < 4; ++r) {
    if (kq == r) {
      float4* dst = reinterpret_cast<float4*>(&souts[lane][oh * 64]);
#pragma unroll
      for (int m4 = 0; m4 < 16; ++m4) {
        float4 v = dst[m4];
        v.x += acc[m4 * 4 + 0]; v.y += acc[m4 * 4 + 1];
        v.z += acc[m4 * 4 + 2]; v.w += acc[m4 * 4 + 3];
        dst[m4] = v;
      }
    }
    __syncthreads();
  }

  // fused epilogue: each wave handles 8 tokens, lane = expert
  const float eb = eb_p[lane];
  const float fl = ws[lane];          // future_load from K1
  const float cb1 = cp_b1[lane];
  const float cw2 = cp_w2[lane];
  const float cb2 = cp_b2[0];
  float psum_local = 0.f, comp_local = 0.f;
  float* o_ts = out;
  float* o_ti = out + 2 * N;
#pragma unroll 1
  for (int tt = 0; tt < 8; ++tt) {
    const int trow = w * 8 + tt;
    const int tok = tb + trow;
    const float lg = souts[trow][lane];
    const float lc = souts[trow][64 + lane];
    // complexity predictor
    float rr = fmaxf(lc + cb1, 0.f) * cw2;
    rr = wsum(rr);
    const float comp = 1.f / (1.f + expf(-(rr + cb2)));
    comp_local += comp;
    // softmax over 64 experts
    float a = lg + eb - fl;
    const float mx = wmax(a);
    const float p = expf(a - mx);
    const float ssum = wsum(p);
    const float prob = p / ssum;
    psum_local += prob;
    // top-2 (tie -> lowest index, matches lax.top_k)
    float v1 = prob; int i1 = lane;
#pragma unroll
    for (int o = 32; o; o >>= 1) {
      const float ov = __shfl_xor(v1, o, 64);
      const int oi = __shfl_xor(i1, o, 64);
      if (ov > v1 || (ov == v1 && oi < i1)) { v1 = ov; i1 = oi; }
    }
    float v2 = (lane == i1) ? -1.f : prob; int i2 = lane;
#pragma unroll
    for (int o = 32; o; o >>= 1) {
      const float ov = __shfl_xor(v2, o, 64);
      const int oi = __shfl_xor(i2, o, 64);
      if (ov > v2 || (ov == v2 && oi < i2)) { v2 = ov; i2 = oi; }
    }
    if (lane == 0) {
      const float inv = 1.f / (v1 + v2);
      o_ts[tok * 2 + 0] = v1 * inv;
      o_ts[tok * 2 + 1] = v2 * inv;
      o_ti[tok * 2 + 0] = (float)i1;
      o_ti[tok * 2 + 1] = (float)i2;
      atomicAdd(&scnt[i1], 1u);
      atomicAdd(&scnt[i2], 1u);
    }
  }
  atomicAdd(&sP[lane], psum_local);
  if (lane == 0) atomicAdd(&scomp, comp_local);
  __syncthreads();
  if (tid < 64) {
    atomicAdd(&ws[64 + tid], sP[tid]);
    atomicAdd(&ws[128 + tid], (float)scnt[tid]);
  }
  if (tid == 0) atomicAdd(&ws[192], scomp);
}

// ---------------- Kernel 3: finalize aux_loss + capacity ----------------
__global__ __launch_bounds__(64) void fin_kernel(const float* __restrict__ ws,
                                                 float* __restrict__ out, int N) {
  const int e = threadIdx.x;
  const float P = ws[64 + e] / (float)N;
  const float f = ws[128 + e] / (float)(2 * N);
  const float v = wsum(f * P);
  if (e == 0) {
    out[4 * N + 0] = 64.f * v;
    float cap = 0.5f + 1.5f * (ws[192] / (float)N);
    out[4 * N + 1] = fminf(fmaxf(cap, 0.5f), 2.f);
  }
}

extern "C" void kernel_launch(void* const* d_in, const int* in_sizes, int n_in,
                              void* d_out, int out_size, void* d_ws, size_t ws_size,
                              hipStream_t stream) {
  const float* x          = (const float*)d_in[0];
  const float* gate_w     = (const float*)d_in[1];
  const float* expert_bias= (const float*)d_in[2];
  const float* cp_w1      = (const float*)d_in[3];
  const float* cp_b1      = (const float*)d_in[4];
  const float* cp_w2      = (const float*)d_in[5];
  const float* cp_b2      = (const float*)d_in[6];
  const float* load_buffer= (const float*)d_in[7];
  const float* wih0       = (const float*)d_in[8];
  const float* whh0       = (const float*)d_in[9];
  const float* bih0       = (const float*)d_in[10];
  const float* bhh0       = (const float*)d_in[11];
  const float* wih1       = (const float*)d_in[12];
  const float* whh1       = (const float*)d_in[13];
  const float* bih1       = (const float*)d_in[14];
  const float* bhh1       = (const float*)d_in[15];
  const float* head_w     = (const float*)d_in[16];
  const float* head_b     = (const float*)d_in[17];
  float* out = (float*)d_out;
  float* ws  = (float*)d_ws;
  const int N = in_sizes[0] / 4096;  // 16384 tokens

  lstm_kernel<<<1, 256, 0, stream>>>(load_buffer, wih0, whh0, bih0, bhh0,
                                     wih1, whh1, bih1, bhh1, head_w, head_b,
                                     ws, out, N);
  moe_kernel<<<N / 64, 512, 0, stream>>>(x, gate_w, expert_bias, cp_w1, cp_b1,
                                         cp_w2, cp_b2, ws, out, N);
  fin_kernel<<<1, 64, 0, stream>>>(ws, out, N);
}